// Round 3
// baseline (454.565 us; speedup 1.0000x reference)
//
#include <hip/hip_runtime.h>
#include <hip/hip_bf16.h>

typedef __bf16 bf16x8 __attribute__((ext_vector_type(8)));
typedef __bf16 bf16x4 __attribute__((ext_vector_type(4)));
typedef float  f32x4  __attribute__((ext_vector_type(4)));
typedef unsigned u32x4 __attribute__((ext_vector_type(4)));

#define B_ 4
#define T_ 2048
#define H_ 16
#define D_ 64
#define C_ 1024
#define M_ 8192                    // B*T
#define NE_ ((size_t)M_ * C_)      // elems per (M,C) tensor

// ---------------------------------------------------------------------------
// Probe: flag=1 if inputs are fp32, flag=0 if bf16.
// ---------------------------------------------------------------------------
__global__ void probe_dtype(const unsigned short* __restrict__ x,
                            int* __restrict__ flag)
{
  __shared__ float red[256];
  float m = 0.0f;
  for (int i = threadIdx.x; i < 4096; i += 256) {
    unsigned int u = ((unsigned int)x[i]) << 16;
    float v = fabsf(__uint_as_float(u));
    if (!(v <= 1e30f)) v = 1e31f;
    m = fmaxf(m, v);
  }
  red[threadIdx.x] = m;
  __syncthreads();
  for (int s = 128; s > 0; s >>= 1) {
    if (threadIdx.x < s) red[threadIdx.x] = fmaxf(red[threadIdx.x], red[threadIdx.x + s]);
    __syncthreads();
  }
  if (threadIdx.x == 0) *flag = (red[0] > 100.0f) ? 1 : 0;
}

__device__ __forceinline__ float load1_adapt(const void* p, size_t idx, int f)
{
  if (f) return ((const float*)p)[idx];
  return __bfloat162float(((const __hip_bfloat16*)p)[idx]);
}

// ---------------------------------------------------------------------------
// Convert a tensor to bf16 (fp32 src if flag, else plain bf16 copy).
// ---------------------------------------------------------------------------
__global__ __launch_bounds__(256) void cvt_bf16(
    const int* __restrict__ flagp, const void* __restrict__ src,
    __bf16* __restrict__ dst, int n)
{
  const int f = *flagp;
  for (size_t i = ((size_t)blockIdx.x * 256 + threadIdx.x) * 8; i < (size_t)n;
       i += (size_t)gridDim.x * 2048) {
    bf16x8 r;
    if (f) {
      const float* pf = (const float*)src + i;
      float4 a = *(const float4*)pf;
      float4 b = *(const float4*)(pf + 4);
      r[0] = (__bf16)a.x; r[1] = (__bf16)a.y; r[2] = (__bf16)a.z; r[3] = (__bf16)a.w;
      r[4] = (__bf16)b.x; r[5] = (__bf16)b.y; r[6] = (__bf16)b.z; r[7] = (__bf16)b.w;
    } else {
      r = *(const bf16x8*)((const __bf16*)src + i);
    }
    *(bf16x8*)(dst + i) = r;
  }
}

// ---------------------------------------------------------------------------
// async 16B global -> LDS copy (gfx950 global_load_lds dwordx4)
// ---------------------------------------------------------------------------
__device__ __forceinline__ void g2lds16(const __bf16* g, __bf16* l)
{
  __builtin_amdgcn_global_load_lds(
      (const __attribute__((address_space(1))) void*)g,
      (__attribute__((address_space(3))) void*)l, 16, 0, 0);
}

// pack two f32 -> one u32 of two bf16 (RNE), single HW instruction
__device__ __forceinline__ unsigned cvtpk_bf16(float lo, float hi)
{
  unsigned r;
  asm("v_cvt_pk_bf16_f32 %0, %1, %2" : "=v"(r) : "v"(lo), "v"(hi));
  return r;
}

// ---------------------------------------------------------------------------
// m97-style GEMM: C = A * Bm^T. A: MxK bf16, Bm: NxK bf16. 128x128 tile,
// BK=64, 4 waves (2x2), global_load_lds width-16 staging (unpadded LDS —
// required by the wave-uniform-base + lane*16 constraint).
// XCD-aware swizzle: nwg=512 divisible by 8.
// Output: bf16, or fp32 when (adaptive && *flagp).
// ---------------------------------------------------------------------------
__global__ __launch_bounds__(256) void gemm128(
    const __bf16* __restrict__ A, const __bf16* __restrict__ Bm,
    void* __restrict__ C, int M, int N, int K,
    const int* __restrict__ flagp, int adaptive)
{
  __shared__ __bf16 As[128][64];
  __shared__ __bf16 Bs[128][64];

  const int tid  = threadIdx.x;
  const int wv   = tid >> 6;
  const int lane = tid & 63;
  const int n16  = lane & 15;
  const int quad = lane >> 4;
  const int wm = (wv & 1) * 64, wn = (wv >> 1) * 64;

  // XCD-aware bijective swizzle (nwg % 8 == 0 for this launch: 64x8=512)
  const int nwgx = gridDim.x;
  const int id   = blockIdx.y * nwgx + blockIdx.x;
  const int cpx  = (nwgx * gridDim.y) >> 3;
  const int swz  = (id & 7) * cpx + (id >> 3);
  const int m0 = (swz % nwgx) * 128, n0 = (swz / nwgx) * 128;

  f32x4 acc[4][4];
#pragma unroll
  for (int i = 0; i < 4; i++)
#pragma unroll
    for (int j = 0; j < 4; j++) acc[i][j] = (f32x4){0.f, 0.f, 0.f, 0.f};

  const int trow = tid >> 3;          // 0..31
  const int tcol = (tid & 7) * 8;     // 0..56

  for (int k0 = 0; k0 < K; k0 += 64) {
#pragma unroll
    for (int p = 0; p < 4; p++) {
      g2lds16(A  + (size_t)(m0 + trow + p * 32) * K + k0 + tcol,
              &As[trow + p * 32][tcol]);
      g2lds16(Bm + (size_t)(n0 + trow + p * 32) * K + k0 + tcol,
              &Bs[trow + p * 32][tcol]);
    }
    __syncthreads();   // drains vmcnt(0): LDS is valid

#pragma unroll
    for (int kk = 0; kk < 2; kk++) {
      bf16x8 af[4], bf[4];
#pragma unroll
      for (int i = 0; i < 4; i++) {
        af[i] = *(const bf16x8*)&As[wm + i * 16 + n16][kk * 32 + quad * 8];
        bf[i] = *(const bf16x8*)&Bs[wn + i * 16 + n16][kk * 32 + quad * 8];
      }
#pragma unroll
      for (int i = 0; i < 4; i++)
#pragma unroll
        for (int j = 0; j < 4; j++)
          acc[i][j] = __builtin_amdgcn_mfma_f32_16x16x32_bf16(af[i], bf[j],
                                                              acc[i][j], 0, 0, 0);
    }
    __syncthreads();
  }

  const int f = adaptive ? *flagp : 0;
  const int rb = quad * 4;
#pragma unroll
  for (int i = 0; i < 4; i++)
#pragma unroll
    for (int j = 0; j < 4; j++)
#pragma unroll
      for (int r = 0; r < 4; r++) {
        const size_t idx = (size_t)(m0 + wm + i * 16 + rb + r) * N
                           + n0 + wn + j * 16 + n16;
        if (f) ((float*)C)[idx] = acc[i][j][r];
        else   ((__bf16*)C)[idx] = (__bf16)acc[i][j][r];
      }
}

// ---------------------------------------------------------------------------
// Fused rmsnorm+RoPE on q,k (bf16, in place) + v mix (bf16 in place, v1 raw).
// ---------------------------------------------------------------------------
__global__ __launch_bounds__(256) void fuse_rope_vmix(
    const int* __restrict__ flagp,
    __hip_bfloat16* __restrict__ q,
    __hip_bfloat16* __restrict__ k,
    __hip_bfloat16* __restrict__ v,
    const void* __restrict__ v1,
    const void* __restrict__ lambp)
{
  const int f    = *flagp;
  const int task = blockIdx.x * 4 + (threadIdx.x >> 6);
  const int lane = threadIdx.x & 63;
  const int h  = task & 15;
  const int bt = task >> 4;
  const int t  = bt & (T_ - 1);
  const size_t base = (size_t)bt * C_ + h * D_ + lane;

  const int j = lane & 31;
  const float inv = expf(-(float)j * (9.2103403719761836f / 32.0f));
  const float ang = (float)t * inv;
  const float cs = cosf(ang), sn = sinf(ang);
  const float EPS = 0.0078125f;

  {
    float xv = __bfloat162float(q[base]);
    float ss = xv * xv;
#pragma unroll
    for (int off = 32; off >= 1; off >>= 1) ss += __shfl_xor(ss, off);
    float r  = rsqrtf(ss * (1.0f / 64.0f) + EPS);
    float xn = xv * r;
    float pr = __shfl_xor(xn, 32);
    float yv = (lane < 32) ? (xn * cs + pr * sn) : (pr * -sn + xn * cs);
    q[base] = __float2bfloat16(yv);
  }
  {
    float xv = __bfloat162float(k[base]);
    float ss = xv * xv;
#pragma unroll
    for (int off = 32; off >= 1; off >>= 1) ss += __shfl_xor(ss, off);
    float r  = rsqrtf(ss * (1.0f / 64.0f) + EPS);
    float xn = xv * r;
    float pr = __shfl_xor(xn, 32);
    float yv = (lane < 32) ? (xn * cs + pr * sn) : (pr * -sn + xn * cs);
    k[base] = __float2bfloat16(yv);
  }
  {
    float lam = load1_adapt(lambp, 0, f);
    float vv  = __bfloat162float(v[base]);
    float v1v = load1_adapt(v1, base, f);
    v[base] = __float2bfloat16((1.0f - lam) * vv + lam * v1v);
  }
}

// ---------------------------------------------------------------------------
// MFMA flash attention fwd (causal). 4 waves, 128 q-rows/block (32/wave as
// two 16-row tiles), K-tile 64. T14 async-STAGE split. FIXED-MAX softmax
// (rmsnorm => S in [-8,8], use max=8: no running max, no rescale).
// SWAPPED OPERANDS (T12): S^T = mfma(K,Q) so each lane holds a q-column of P
// in registers; P^T redistributed to the PV B-fragment in-register via
// cvt_pk_bf16 + ds_bpermute (__shfl) + select — NO P LDS round-trip, no
// lgkm drain, no l-MFMAs (l accumulates lane-locally, 2-shuffle reduce at
// end). PV: O^T = mfma(V^T-frag, P^T-frag), same VTs reads as before.
// Heavy blocks first. y aliases q.
// ---------------------------------------------------------------------------
__global__ __launch_bounds__(256) void attn_mfma(
    const __bf16* q,
    const __bf16* __restrict__ k,
    const __bf16* __restrict__ v,
    __bf16* y)
{
  __shared__ alignas(16) __bf16 Ks[64][72];     // [s][d]
  __shared__ alignas(16) __bf16 VTs[64][88];    // [d][s]

  const int tid  = threadIdx.x;
  const int wv   = tid >> 6;
  const int lane = tid & 63;
  const int n16  = lane & 15;
  const int quad = lane >> 4;
  const int b = blockIdx.y >> 4, h = blockIdx.y & 15;
  const int q0 = (gridDim.x - 1 - blockIdx.x) * 128;   // heavy blocks first
  const size_t hb = (size_t)b * T_ * C_ + h * D_;

  // ---- Q fragments (B-operand of swapped QK): lane holds Q[rbase+n16][d]
  bf16x8 aq[2][2];
#pragma unroll
  for (int rt = 0; rt < 2; rt++) {
    const size_t qoff = hb + (size_t)(q0 + wv * 32 + rt * 16 + n16) * C_;
    aq[rt][0] = *(const bf16x8*)(q + qoff + quad * 8);
    aq[rt][1] = *(const bf16x8*)(q + qoff + 32 + quad * 8);
#pragma unroll
    for (int jj = 0; jj < 8; jj++) {
      aq[rt][0][jj] = (__bf16)((float)aq[rt][0][jj] * 0.125f);
      aq[rt][1][jj] = (__bf16)((float)aq[rt][1][jj] * 0.125f);
    }
  }

  f32x4 Ot[2][4];                 // Ot[rt][t][r] = O^T[d=16t+quad*4+r, q=n16]
  float l_lane[2];
#pragma unroll
  for (int rt = 0; rt < 2; rt++) {
    l_lane[rt] = 0.0f;
#pragma unroll
    for (int t = 0; t < 4; t++) Ot[rt][t] = (f32x4){0.f, 0.f, 0.f, 0.f};
  }

  // staging thread->slot maps
  const int trow = tid >> 2;          // K: 0..63
  const int tcol = (tid & 3) * 16;    // K: 0,16,32,48

  // P redistribution lane constants
  const int srcA = n16 + 32 * (quad & 1);     // src quad 2*(q&1)
  const int srcB = srcA + 16;                 // src quad 2*(q&1)+1
  const bool lowq = quad < 2;                 // t' = 2c (else 2c+1)

  const int niter = q0 / 64 + 2;      // s-tiles cover 0 .. q0+127

  // ---- prologue: stage tile 0 ----
  bf16x8 kr0, kr1, vr0, vr1;
  {
    const __bf16* ks = k + hb + (size_t)trow * C_ + tcol;
    kr0 = *(const bf16x8*)(ks);
    kr1 = *(const bf16x8*)(ks + 8);
    const __bf16* vs = v + hb + (size_t)lane * C_;
    vr0 = *(const bf16x8*)(vs + wv * 8);
    vr1 = *(const bf16x8*)(vs + (wv + 4) * 8);
    *(bf16x8*)&Ks[trow][tcol]     = kr0;
    *(bf16x8*)&Ks[trow][tcol + 8] = kr1;
#pragma unroll
    for (int jj = 0; jj < 8; jj++) VTs[wv * 8 + jj][lane] = vr0[jj];
#pragma unroll
    for (int jj = 0; jj < 8; jj++) VTs[(wv + 4) * 8 + jj][lane] = vr1[jj];
  }
  __syncthreads();

  for (int it = 0; it < niter; it++) {
    const int s0 = it * 64;
    const bool havenext = (it + 1 < niter);

    // ---- issue next tile's global loads NOW (latency hides under compute)
    if (havenext) {
      const int sn = s0 + 64;
      const __bf16* ks = k + hb + (size_t)(sn + trow) * C_ + tcol;
      kr0 = *(const bf16x8*)(ks);
      kr1 = *(const bf16x8*)(ks + 8);
      const __bf16* vs = v + hb + (size_t)(sn + lane) * C_;
      vr0 = *(const bf16x8*)(vs + wv * 8);
      vr1 = *(const bf16x8*)(vs + (wv + 4) * 8);
    }

    // ---- compute current tile (skip if fully above this wave's diagonal)
    if (s0 <= q0 + wv * 32 + 31) {
#pragma unroll
      for (int rt = 0; rt < 2; rt++) {
        const int rbase = q0 + wv * 32 + rt * 16;
        if (s0 <= rbase + 15) {
          // ---- S^T = K Q^T : lane holds S[q=rbase+n16, s=s0+16t+quad*4+r]
          f32x4 S[4];
          __builtin_amdgcn_s_setprio(1);
#pragma unroll
          for (int t = 0; t < 4; t++) {
            S[t] = (f32x4){0.f, 0.f, 0.f, 0.f};
            bf16x8 b0 = *(const bf16x8*)&Ks[t * 16 + n16][quad * 8];
            bf16x8 b1 = *(const bf16x8*)&Ks[t * 16 + n16][32 + quad * 8];
            S[t] = __builtin_amdgcn_mfma_f32_16x16x32_bf16(b0, aq[rt][0], S[t], 0, 0, 0);
            S[t] = __builtin_amdgcn_mfma_f32_16x16x32_bf16(b1, aq[rt][1], S[t], 0, 0, 0);
          }
          __builtin_amdgcn_s_setprio(0);

          // ---- causal mask (only when tile crosses this row-tile's diagonal)
          if (s0 + 63 > rbase) {
            const int tg = rbase + n16;
#pragma unroll
            for (int t = 0; t < 4; t++) {
#pragma unroll
              for (int r = 0; r < 4; r++) {
                const int sg = s0 + t * 16 + quad * 4 + r;
                if (sg > tg) S[t][r] = -1e30f;
              }
            }
          }

          // ---- fixed-max softmax: p = exp(S - 8); l accumulates in-lane
          float p[4][4];
#pragma unroll
          for (int t = 0; t < 4; t++)
#pragma unroll
            for (int r = 0; r < 4; r++)
              p[t][r] = __expf(S[t][r] - 8.0f);
          l_lane[rt] += ((p[0][0] + p[0][1]) + (p[0][2] + p[0][3]))
                      + ((p[1][0] + p[1][1]) + (p[1][2] + p[1][3]))
                      + ((p[2][0] + p[2][1]) + (p[2][2] + p[2][3]))
                      + ((p[3][0] + p[3][1]) + (p[3][2] + p[3][3]));

          // ---- pack to bf16 pairs: pk[t][h] = (p[t][2h], p[t][2h+1])
          unsigned pk0[4], pk1[4];
#pragma unroll
          for (int t = 0; t < 4; t++) {
            pk0[t] = cvtpk_bf16(p[t][0], p[t][1]);
            pk1[t] = cvtpk_bf16(p[t][2], p[t][3]);
          }

          // ---- in-register redistribution to PV B-fragments
          // dst lane (n16,q) word w of chunk c = P^T[s=32c+8q+2w', q=n16] pair
          bf16x8 pf[2];
#pragma unroll
          for (int c = 0; c < 2; c++) {
            const int tE = 2 * c, tO = 2 * c + 1;
            unsigned a0 = (unsigned)__shfl((int)pk0[tE], srcA);
            unsigned a1 = (unsigned)__shfl((int)pk0[tO], srcA);
            unsigned b0 = (unsigned)__shfl((int)pk1[tE], srcA);
            unsigned b1 = (unsigned)__shfl((int)pk1[tO], srcA);
            unsigned c0 = (unsigned)__shfl((int)pk0[tE], srcB);
            unsigned c1 = (unsigned)__shfl((int)pk0[tO], srcB);
            unsigned d0 = (unsigned)__shfl((int)pk1[tE], srcB);
            unsigned d1 = (unsigned)__shfl((int)pk1[tO], srcB);
            union { u32x4 u; bf16x8 b; } uw;
            uw.u[0] = lowq ? a0 : a1;   // j=0,1
            uw.u[1] = lowq ? b0 : b1;   // j=2,3
            uw.u[2] = lowq ? c0 : c1;   // j=4,5
            uw.u[3] = lowq ? d0 : d1;   // j=6,7
            pf[c] = uw.b;
          }

          // ---- O^T += V^T P^T (A = VTs rows, B = pf) ----
          __builtin_amdgcn_s_setprio(1);
#pragma unroll
          for (int t = 0; t < 4; t++) {
            bf16x8 va0 = *(const bf16x8*)&VTs[t * 16 + n16][quad * 8];
            bf16x8 va1 = *(const bf16x8*)&VTs[t * 16 + n16][32 + quad * 8];
            Ot[rt][t] = __builtin_amdgcn_mfma_f32_16x16x32_bf16(va0, pf[0], Ot[rt][t], 0, 0, 0);
            Ot[rt][t] = __builtin_amdgcn_mfma_f32_16x16x32_bf16(va1, pf[1], Ot[rt][t], 0, 0, 0);
          }
          __builtin_amdgcn_s_setprio(0);
        }
      }
    }

    __syncthreads();             // everyone done reading Ks/VTs
    if (havenext) {              // write-late: regs -> LDS (vmcnt wait is short)
      *(bf16x8*)&Ks[trow][tcol]     = kr0;
      *(bf16x8*)&Ks[trow][tcol + 8] = kr1;
#pragma unroll
      for (int jj = 0; jj < 8; jj++) VTs[wv * 8 + jj][lane] = vr0[jj];
#pragma unroll
      for (int jj = 0; jj < 8; jj++) VTs[(wv + 4) * 8 + jj][lane] = vr1[jj];
    }
    __syncthreads();             // LDS valid for next iteration
  }

  // ---- epilogue: reduce l across quads (same n16 = same q-row), write O
#pragma unroll
  for (int rt = 0; rt < 2; rt++) {
    float lt = l_lane[rt];
    lt += __shfl_xor(lt, 16);
    lt += __shfl_xor(lt, 32);
    const float linv = 1.0f / lt;
    const int qrow = q0 + wv * 32 + rt * 16 + n16;
#pragma unroll
    for (int t = 0; t < 4; t++) {
      bf16x4 o;
#pragma unroll
      for (int r = 0; r < 4; r++) o[r] = (__bf16)(Ot[rt][t][r] * linv);
      *(bf16x4*)(y + hb + (size_t)qrow * C_ + t * 16 + quad * 4) = o;
    }
  }
}

// ---------------------------------------------------------------------------
__global__ __launch_bounds__(256) void copy_v1(
    const int* __restrict__ flagp, const void* __restrict__ v1, void* __restrict__ out)
{
  const int f = *flagp;
  const size_t nbytes = NE_ * (f ? 4u : 2u);
  const uint4* s = (const uint4*)v1;
  uint4* d = (uint4*)((char*)out + nbytes);
  const size_t n16 = nbytes / 16;
  for (size_t i = (size_t)blockIdx.x * 256 + threadIdx.x; i < n16;
       i += (size_t)gridDim.x * 256)
    d[i] = s[i];
}

// ---------------------------------------------------------------------------
extern "C" void kernel_launch(void* const* d_in, const int* in_sizes, int n_in,
                              void* d_out, int out_size, void* d_ws, size_t ws_size,
                              hipStream_t stream)
{
  const void* x    = d_in[0];
  const void* v1   = d_in[1];
  const void* Wq   = d_in[2];
  const void* Wk   = d_in[3];
  const void* Wv   = d_in[4];
  const void* Wp   = d_in[5];
  const void* lamb = d_in[6];

  // ws layout (bf16): xb | qw | Wq | Wk | Wv | Wp | flag  (~42 MB)
  __bf16* xb  = (__bf16*)d_ws;
  __bf16* qw  = xb + NE_;
  __bf16* wqb = qw + NE_;
  __bf16* wkb = wqb + (size_t)C_ * C_;
  __bf16* wvb = wkb + (size_t)C_ * C_;
  __bf16* wpb = wvb + (size_t)C_ * C_;
  int* flagp  = (int*)(wpb + (size_t)C_ * C_);
  // k, v staging in d_out (safe under both dtypes; dead before final writes)
  __bf16* kw = (__bf16*)d_out;
  __bf16* vw = (__bf16*)((char*)d_out + NE_ * 2);

  probe_dtype<<<1, 256, 0, stream>>>((const unsigned short*)x, flagp);

  cvt_bf16<<<4096, 256, 0, stream>>>(flagp, x,  xb,  (int)NE_);
  cvt_bf16<<<512,  256, 0, stream>>>(flagp, Wq, wqb, C_ * C_);
  cvt_bf16<<<512,  256, 0, stream>>>(flagp, Wk, wkb, C_ * C_);
  cvt_bf16<<<512,  256, 0, stream>>>(flagp, Wv, wvb, C_ * C_);
  cvt_bf16<<<512,  256, 0, stream>>>(flagp, Wp, wpb, C_ * C_);

  dim3 gg(M_ / 128, C_ / 128);
  gemm128<<<gg, 256, 0, stream>>>(xb, wqb, qw, M_, C_, C_, flagp, 0);
  gemm128<<<gg, 256, 0, stream>>>(xb, wkb, kw, M_, C_, C_, flagp, 0);
  gemm128<<<gg, 256, 0, stream>>>(xb, wvb, vw, M_, C_, C_, flagp, 0);

  fuse_rope_vmix<<<(M_ * H_) / 4, 256, 0, stream>>>(
      flagp, (__hip_bfloat16*)qw, (__hip_bfloat16*)kw, (__hip_bfloat16*)vw,
      v1, lamb);

  attn_mfma<<<dim3(T_ / 128, B_ * H_), 256, 0, stream>>>(qw, kw, vw, qw);

  gemm128<<<gg, 256, 0, stream>>>(qw, wpb, d_out, M_, C_, C_, flagp, 1);
  copy_v1<<<8192, 256, 0, stream>>>(flagp, v1, d_out);
}

// Round 4
// 448.690 us; speedup vs baseline: 1.0131x; 1.0131x over previous
//
#include <hip/hip_runtime.h>
#include <hip/hip_bf16.h>

typedef __bf16 bf16x8 __attribute__((ext_vector_type(8)));
typedef __bf16 bf16x4 __attribute__((ext_vector_type(4)));
typedef float  f32x4  __attribute__((ext_vector_type(4)));
typedef unsigned u32x4 __attribute__((ext_vector_type(4)));

#define B_ 4
#define T_ 2048
#define H_ 16
#define D_ 64
#define C_ 1024
#define M_ 8192                    // B*T
#define NE_ ((size_t)M_ * C_)      // elems per (M,C) tensor

// ---------------------------------------------------------------------------
// Probe: flag=1 if inputs are fp32, flag=0 if bf16.
// ---------------------------------------------------------------------------
__global__ void probe_dtype(const unsigned short* __restrict__ x,
                            int* __restrict__ flag)
{
  __shared__ float red[256];
  float m = 0.0f;
  for (int i = threadIdx.x; i < 4096; i += 256) {
    unsigned int u = ((unsigned int)x[i]) << 16;
    float v = fabsf(__uint_as_float(u));
    if (!(v <= 1e30f)) v = 1e31f;
    m = fmaxf(m, v);
  }
  red[threadIdx.x] = m;
  __syncthreads();
  for (int s = 128; s > 0; s >>= 1) {
    if (threadIdx.x < s) red[threadIdx.x] = fmaxf(red[threadIdx.x], red[threadIdx.x + s]);
    __syncthreads();
  }
  if (threadIdx.x == 0) *flag = (red[0] > 100.0f) ? 1 : 0;
}

__device__ __forceinline__ float load1_adapt(const void* p, size_t idx, int f)
{
  if (f) return ((const float*)p)[idx];
  return __bfloat162float(((const __hip_bfloat16*)p)[idx]);
}

// ---------------------------------------------------------------------------
// Convert a tensor to bf16 (fp32 src if flag, else plain bf16 copy).
// ---------------------------------------------------------------------------
__global__ __launch_bounds__(256) void cvt_bf16(
    const int* __restrict__ flagp, const void* __restrict__ src,
    __bf16* __restrict__ dst, int n)
{
  const int f = *flagp;
  for (size_t i = ((size_t)blockIdx.x * 256 + threadIdx.x) * 8; i < (size_t)n;
       i += (size_t)gridDim.x * 2048) {
    bf16x8 r;
    if (f) {
      const float* pf = (const float*)src + i;
      float4 a = *(const float4*)pf;
      float4 b = *(const float4*)(pf + 4);
      r[0] = (__bf16)a.x; r[1] = (__bf16)a.y; r[2] = (__bf16)a.z; r[3] = (__bf16)a.w;
      r[4] = (__bf16)b.x; r[5] = (__bf16)b.y; r[6] = (__bf16)b.z; r[7] = (__bf16)b.w;
    } else {
      r = *(const bf16x8*)((const __bf16*)src + i);
    }
    *(bf16x8*)(dst + i) = r;
  }
}

// ---------------------------------------------------------------------------
// async 16B global -> LDS copy (gfx950 global_load_lds dwordx4)
// ---------------------------------------------------------------------------
__device__ __forceinline__ void g2lds16(const __bf16* g, __bf16* l)
{
  __builtin_amdgcn_global_load_lds(
      (const __attribute__((address_space(1))) void*)g,
      (__attribute__((address_space(3))) void*)l, 16, 0, 0);
}

// pack two f32 -> one u32 of two bf16 (RNE), single HW instruction
__device__ __forceinline__ unsigned cvtpk_bf16(float lo, float hi)
{
  unsigned r;
  asm("v_cvt_pk_bf16_f32 %0, %1, %2" : "=v"(r) : "v"(lo), "v"(hi));
  return r;
}

// ---------------------------------------------------------------------------
// m97-style GEMM: C = A * Bm^T. A: MxK bf16, Bm: NxK bf16. 128x128 tile,
// BK=64, 4 waves (2x2), global_load_lds width-16 staging (unpadded LDS —
// required by the wave-uniform-base + lane*16 constraint).
// XCD-aware swizzle: nwg=512 divisible by 8.
// Output: bf16, or fp32 when (adaptive && *flagp).
// ---------------------------------------------------------------------------
__global__ __launch_bounds__(256) void gemm128(
    const __bf16* __restrict__ A, const __bf16* __restrict__ Bm,
    void* __restrict__ C, int M, int N, int K,
    const int* __restrict__ flagp, int adaptive)
{
  __shared__ __bf16 As[128][64];
  __shared__ __bf16 Bs[128][64];

  const int tid  = threadIdx.x;
  const int wv   = tid >> 6;
  const int lane = tid & 63;
  const int n16  = lane & 15;
  const int quad = lane >> 4;
  const int wm = (wv & 1) * 64, wn = (wv >> 1) * 64;

  // XCD-aware bijective swizzle (nwg % 8 == 0 for this launch: 64x8=512)
  const int nwgx = gridDim.x;
  const int id   = blockIdx.y * nwgx + blockIdx.x;
  const int cpx  = (nwgx * gridDim.y) >> 3;
  const int swz  = (id & 7) * cpx + (id >> 3);
  const int m0 = (swz % nwgx) * 128, n0 = (swz / nwgx) * 128;

  f32x4 acc[4][4];
#pragma unroll
  for (int i = 0; i < 4; i++)
#pragma unroll
    for (int j = 0; j < 4; j++) acc[i][j] = (f32x4){0.f, 0.f, 0.f, 0.f};

  const int trow = tid >> 3;          // 0..31
  const int tcol = (tid & 7) * 8;     // 0..56

  for (int k0 = 0; k0 < K; k0 += 64) {
#pragma unroll
    for (int p = 0; p < 4; p++) {
      g2lds16(A  + (size_t)(m0 + trow + p * 32) * K + k0 + tcol,
              &As[trow + p * 32][tcol]);
      g2lds16(Bm + (size_t)(n0 + trow + p * 32) * K + k0 + tcol,
              &Bs[trow + p * 32][tcol]);
    }
    __syncthreads();   // drains vmcnt(0): LDS is valid

#pragma unroll
    for (int kk = 0; kk < 2; kk++) {
      bf16x8 af[4], bf[4];
#pragma unroll
      for (int i = 0; i < 4; i++) {
        af[i] = *(const bf16x8*)&As[wm + i * 16 + n16][kk * 32 + quad * 8];
        bf[i] = *(const bf16x8*)&Bs[wn + i * 16 + n16][kk * 32 + quad * 8];
      }
#pragma unroll
      for (int i = 0; i < 4; i++)
#pragma unroll
        for (int j = 0; j < 4; j++)
          acc[i][j] = __builtin_amdgcn_mfma_f32_16x16x32_bf16(af[i], bf[j],
                                                              acc[i][j], 0, 0, 0);
    }
    __syncthreads();
  }

  const int f = adaptive ? *flagp : 0;
  const int rb = quad * 4;
#pragma unroll
  for (int i = 0; i < 4; i++)
#pragma unroll
    for (int j = 0; j < 4; j++)
#pragma unroll
      for (int r = 0; r < 4; r++) {
        const size_t idx = (size_t)(m0 + wm + i * 16 + rb + r) * N
                           + n0 + wn + j * 16 + n16;
        if (f) ((float*)C)[idx] = acc[i][j][r];
        else   ((__bf16*)C)[idx] = (__bf16)acc[i][j][r];
      }
}

// ---------------------------------------------------------------------------
// Fused rmsnorm+RoPE on q,k (bf16, in place) + v mix (bf16 in place, v1 raw).
// ---------------------------------------------------------------------------
__global__ __launch_bounds__(256) void fuse_rope_vmix(
    const int* __restrict__ flagp,
    __hip_bfloat16* __restrict__ q,
    __hip_bfloat16* __restrict__ k,
    __hip_bfloat16* __restrict__ v,
    const void* __restrict__ v1,
    const void* __restrict__ lambp)
{
  const int f    = *flagp;
  const int task = blockIdx.x * 4 + (threadIdx.x >> 6);
  const int lane = threadIdx.x & 63;
  const int h  = task & 15;
  const int bt = task >> 4;
  const int t  = bt & (T_ - 1);
  const size_t base = (size_t)bt * C_ + h * D_ + lane;

  const int j = lane & 31;
  const float inv = expf(-(float)j * (9.2103403719761836f / 32.0f));
  const float ang = (float)t * inv;
  const float cs = cosf(ang), sn = sinf(ang);
  const float EPS = 0.0078125f;

  {
    float xv = __bfloat162float(q[base]);
    float ss = xv * xv;
#pragma unroll
    for (int off = 32; off >= 1; off >>= 1) ss += __shfl_xor(ss, off);
    float r  = rsqrtf(ss * (1.0f / 64.0f) + EPS);
    float xn = xv * r;
    float pr = __shfl_xor(xn, 32);
    float yv = (lane < 32) ? (xn * cs + pr * sn) : (pr * -sn + xn * cs);
    q[base] = __float2bfloat16(yv);
  }
  {
    float xv = __bfloat162float(k[base]);
    float ss = xv * xv;
#pragma unroll
    for (int off = 32; off >= 1; off >>= 1) ss += __shfl_xor(ss, off);
    float r  = rsqrtf(ss * (1.0f / 64.0f) + EPS);
    float xn = xv * r;
    float pr = __shfl_xor(xn, 32);
    float yv = (lane < 32) ? (xn * cs + pr * sn) : (pr * -sn + xn * cs);
    k[base] = __float2bfloat16(yv);
  }
  {
    float lam = load1_adapt(lambp, 0, f);
    float vv  = __bfloat162float(v[base]);
    float v1v = load1_adapt(v1, base, f);
    v[base] = __float2bfloat16((1.0f - lam) * vv + lam * v1v);
  }
}

// ---------------------------------------------------------------------------
// Transpose mixed V (M,C layout) -> VT [b*16+h][d][t]  (head-major, row = d,
// contiguous in t). 64x64 tiles via LDS. Output rows feed attn PV A-frags
// with coalesced 16B loads.
// ---------------------------------------------------------------------------
__global__ __launch_bounds__(256) void transp_v(
    const __bf16* __restrict__ v, __bf16* __restrict__ vt)
{
  __shared__ __bf16 Ts[64][72];
  const int bh = blockIdx.y;          // 0..63
  const int t0 = blockIdx.x * 64;
  const int b = bh >> 4, h = bh & 15;

  const int r = threadIdx.x >> 2;           // 0..63 (t-local)
  const int c = (threadIdx.x & 3) * 16;     // 0,16,32,48 (d)
  const __bf16* src = v + (size_t)(b * T_ + t0 + r) * C_ + h * D_ + c;
  *(bf16x8*)&Ts[r][c]     = *(const bf16x8*)src;
  *(bf16x8*)&Ts[r][c + 8] = *(const bf16x8*)(src + 8);
  __syncthreads();

  const int d  = threadIdx.x >> 2;          // 0..63
  const int tc = (threadIdx.x & 3) * 16;    // t-chunk
  bf16x8 o0, o1;
#pragma unroll
  for (int jj = 0; jj < 8; jj++) { o0[jj] = Ts[tc + jj][d]; o1[jj] = Ts[tc + 8 + jj][d]; }
  __bf16* dst = vt + (size_t)(bh * D_ + d) * T_ + t0 + tc;
  *(bf16x8*)dst       = o0;
  *(bf16x8*)(dst + 8) = o1;
}

// ---------------------------------------------------------------------------
// MFMA flash attention fwd (causal), BARRIER-FREE / LDS-FREE.
// K/V per head = 256KB each -> L2-resident; staging them in LDS was pure
// overhead (m214 #7). Each wave owns 32 q-rows (2 rt-tiles), iterates its own
// s-range independently: K frags read directly from global, V^T frags from
// the pre-transposed VT tensor. Fragments shared across both rt-tiles.
// FIXED-MAX softmax (rmsnorm => S in [-8,8]). Swapped operands throughout;
// P^T redistributed in-register (cvt_pk + bpermute + select).
// Swizzle: all 16 blocks of a head land on one XCD (K/V pinned in its L2),
// heaviest block of every head dispatched first. y aliases q.
// ---------------------------------------------------------------------------
__global__ __launch_bounds__(256, 3) void attn_mfma(
    const __bf16* q,
    const __bf16* __restrict__ k,
    const __bf16* __restrict__ vt,
    __bf16* y)
{
  const int tid  = threadIdx.x;
  const int wv   = tid >> 6;
  const int lane = tid & 63;
  const int n16  = lane & 15;
  const int quad = lane >> 4;

  // swizzle: id%8 = head%8 (same XCD under round-robin); bx = id>>6 so the
  // heaviest block of each head is dispatched first.
  const int id = blockIdx.y * gridDim.x + blockIdx.x;   // 0..1023
  const int bh = (id & 7) + 8 * ((id >> 3) & 7);        // 0..63
  const int bx = id >> 6;                               // 0..15
  const int b = bh >> 4, h = bh & 15;
  const int q0 = (gridDim.x - 1 - bx) * 128;            // heavy first
  const size_t hb  = (size_t)b * T_ * C_ + h * D_;
  const size_t vhb = (size_t)bh * D_ * T_;

  // ---- Q fragments (B-operand of swapped QK), pre-scaled by 1/8 ----
  bf16x8 aq[2][2];
#pragma unroll
  for (int rt = 0; rt < 2; rt++) {
    const size_t qoff = hb + (size_t)(q0 + wv * 32 + rt * 16 + n16) * C_;
    aq[rt][0] = *(const bf16x8*)(q + qoff + quad * 8);
    aq[rt][1] = *(const bf16x8*)(q + qoff + 32 + quad * 8);
#pragma unroll
    for (int jj = 0; jj < 8; jj++) {
      aq[rt][0][jj] = (__bf16)((float)aq[rt][0][jj] * 0.125f);
      aq[rt][1][jj] = (__bf16)((float)aq[rt][1][jj] * 0.125f);
    }
  }

  f32x4 Ot[2][4];                 // Ot[rt][t][r] = O^T[d=16t+quad*4+r, q=n16]
  float l_lane[2];
#pragma unroll
  for (int rt = 0; rt < 2; rt++) {
    l_lane[rt] = 0.0f;
#pragma unroll
    for (int t = 0; t < 4; t++) Ot[rt][t] = (f32x4){0.f, 0.f, 0.f, 0.f};
  }

  // P redistribution lane constants
  const int srcA = n16 + 32 * (quad & 1);
  const int srcB = srcA + 16;
  const bool lowq = quad < 2;

  const int rbase0 = q0 + wv * 32;
  const int niter  = (rbase0 + 31) / 64 + 1;   // per-wave s-range!

  for (int it = 0; it < niter; it++) {
    const int s0 = it * 64;

    // ---- K and V^T fragments straight from global (L2-resident) ----
    bf16x8 kf[4][2], vf[4][2];
#pragma unroll
    for (int t = 0; t < 4; t++) {
      const __bf16* kp = k + hb + (size_t)(s0 + t * 16 + n16) * C_;
      kf[t][0] = *(const bf16x8*)(kp + quad * 8);
      kf[t][1] = *(const bf16x8*)(kp + 32 + quad * 8);
      const __bf16* vp = vt + vhb + (size_t)(t * 16 + n16) * T_ + s0;
      vf[t][0] = *(const bf16x8*)(vp + quad * 8);
      vf[t][1] = *(const bf16x8*)(vp + 32 + quad * 8);
    }

#pragma unroll
    for (int rt = 0; rt < 2; rt++) {
      const int rbase = rbase0 + rt * 16;
      if (s0 <= rbase + 15) {
        // ---- S^T = K Q^T : lane holds S[q=rbase+n16, s=s0+16t+quad*4+r]
        f32x4 S[4];
        __builtin_amdgcn_s_setprio(1);
#pragma unroll
        for (int t = 0; t < 4; t++) {
          S[t] = (f32x4){0.f, 0.f, 0.f, 0.f};
          S[t] = __builtin_amdgcn_mfma_f32_16x16x32_bf16(kf[t][0], aq[rt][0], S[t], 0, 0, 0);
          S[t] = __builtin_amdgcn_mfma_f32_16x16x32_bf16(kf[t][1], aq[rt][1], S[t], 0, 0, 0);
        }
        __builtin_amdgcn_s_setprio(0);

        // ---- causal mask (only when tile crosses this row-tile's diagonal)
        if (s0 + 63 > rbase) {
          const int tg = rbase + n16;
#pragma unroll
          for (int t = 0; t < 4; t++) {
#pragma unroll
            for (int r = 0; r < 4; r++) {
              const int sg = s0 + t * 16 + quad * 4 + r;
              if (sg > tg) S[t][r] = -1e30f;
            }
          }
        }

        // ---- fixed-max softmax: p = exp(S - 8); l accumulates in-lane
        float p[4][4];
#pragma unroll
        for (int t = 0; t < 4; t++)
#pragma unroll
          for (int r = 0; r < 4; r++)
            p[t][r] = __expf(S[t][r] - 8.0f);
        l_lane[rt] += ((p[0][0] + p[0][1]) + (p[0][2] + p[0][3]))
                    + ((p[1][0] + p[1][1]) + (p[1][2] + p[1][3]))
                    + ((p[2][0] + p[2][1]) + (p[2][2] + p[2][3]))
                    + ((p[3][0] + p[3][1]) + (p[3][2] + p[3][3]));

        // ---- pack to bf16 pairs ----
        unsigned pk0[4], pk1[4];
#pragma unroll
        for (int t = 0; t < 4; t++) {
          pk0[t] = cvtpk_bf16(p[t][0], p[t][1]);
          pk1[t] = cvtpk_bf16(p[t][2], p[t][3]);
        }

        // ---- in-register redistribution to PV B-fragments ----
        bf16x8 pf[2];
#pragma unroll
        for (int c = 0; c < 2; c++) {
          const int tE = 2 * c, tO = 2 * c + 1;
          unsigned a0 = (unsigned)__shfl((int)pk0[tE], srcA);
          unsigned a1 = (unsigned)__shfl((int)pk0[tO], srcA);
          unsigned b0 = (unsigned)__shfl((int)pk1[tE], srcA);
          unsigned b1 = (unsigned)__shfl((int)pk1[tO], srcA);
          unsigned c0 = (unsigned)__shfl((int)pk0[tE], srcB);
          unsigned c1 = (unsigned)__shfl((int)pk0[tO], srcB);
          unsigned d0 = (unsigned)__shfl((int)pk1[tE], srcB);
          unsigned d1 = (unsigned)__shfl((int)pk1[tO], srcB);
          union { u32x4 u; bf16x8 bv; } uw;
          uw.u[0] = lowq ? a0 : a1;
          uw.u[1] = lowq ? b0 : b1;
          uw.u[2] = lowq ? c0 : c1;
          uw.u[3] = lowq ? d0 : d1;
          pf[c] = uw.bv;
        }

        // ---- O^T += V^T P^T (A = vf, B = pf) ----
        __builtin_amdgcn_s_setprio(1);
#pragma unroll
        for (int t = 0; t < 4; t++) {
          Ot[rt][t] = __builtin_amdgcn_mfma_f32_16x16x32_bf16(vf[t][0], pf[0], Ot[rt][t], 0, 0, 0);
          Ot[rt][t] = __builtin_amdgcn_mfma_f32_16x16x32_bf16(vf[t][1], pf[1], Ot[rt][t], 0, 0, 0);
        }
        __builtin_amdgcn_s_setprio(0);
      }
    }
  }

  // ---- epilogue: reduce l across quads (same n16 = same q-row), write O
#pragma unroll
  for (int rt = 0; rt < 2; rt++) {
    float lt = l_lane[rt];
    lt += __shfl_xor(lt, 16);
    lt += __shfl_xor(lt, 32);
    const float linv = 1.0f / lt;
    const int qrow = q0 + wv * 32 + rt * 16 + n16;
#pragma unroll
    for (int t = 0; t < 4; t++) {
      bf16x4 o;
#pragma unroll
      for (int r = 0; r < 4; r++) o[r] = (__bf16)(Ot[rt][t][r] * linv);
      *(bf16x4*)(y + hb + (size_t)qrow * C_ + t * 16 + quad * 4) = o;
    }
  }
}

// ---------------------------------------------------------------------------
__global__ __launch_bounds__(256) void copy_v1(
    const int* __restrict__ flagp, const void* __restrict__ v1, void* __restrict__ out)
{
  const int f = *flagp;
  const size_t nbytes = NE_ * (f ? 4u : 2u);
  const uint4* s = (const uint4*)v1;
  uint4* d = (uint4*)((char*)out + nbytes);
  const size_t n16 = nbytes / 16;
  for (size_t i = (size_t)blockIdx.x * 256 + threadIdx.x; i < n16;
       i += (size_t)gridDim.x * 256)
    d[i] = s[i];
}

// ---------------------------------------------------------------------------
extern "C" void kernel_launch(void* const* d_in, const int* in_sizes, int n_in,
                              void* d_out, int out_size, void* d_ws, size_t ws_size,
                              hipStream_t stream)
{
  const void* x    = d_in[0];
  const void* v1   = d_in[1];
  const void* Wq   = d_in[2];
  const void* Wk   = d_in[3];
  const void* Wv   = d_in[4];
  const void* Wp   = d_in[5];
  const void* lamb = d_in[6];

  // ws layout (bf16): xb | qw | Wq | Wk | Wv | Wp | flag  (~42 MB)
  // xb is dead after the QKV GEMMs -> reused as VT (exactly NE_ elems).
  __bf16* xb  = (__bf16*)d_ws;
  __bf16* qw  = xb + NE_;
  __bf16* wqb = qw + NE_;
  __bf16* wkb = wqb + (size_t)C_ * C_;
  __bf16* wvb = wkb + (size_t)C_ * C_;
  __bf16* wpb = wvb + (size_t)C_ * C_;
  int* flagp  = (int*)(wpb + (size_t)C_ * C_);
  __bf16* vtb = xb;                       // VT alias (16 MB)
  // k, v staging in d_out (safe under both dtypes; dead before final writes)
  __bf16* kw = (__bf16*)d_out;
  __bf16* vw = (__bf16*)((char*)d_out + NE_ * 2);

  probe_dtype<<<1, 256, 0, stream>>>((const unsigned short*)x, flagp);

  cvt_bf16<<<4096, 256, 0, stream>>>(flagp, x,  xb,  (int)NE_);
  cvt_bf16<<<512,  256, 0, stream>>>(flagp, Wq, wqb, C_ * C_);
  cvt_bf16<<<512,  256, 0, stream>>>(flagp, Wk, wkb, C_ * C_);
  cvt_bf16<<<512,  256, 0, stream>>>(flagp, Wv, wvb, C_ * C_);
  cvt_bf16<<<512,  256, 0, stream>>>(flagp, Wp, wpb, C_ * C_);

  dim3 gg(M_ / 128, C_ / 128);
  gemm128<<<gg, 256, 0, stream>>>(xb, wqb, qw, M_, C_, C_, flagp, 0);
  gemm128<<<gg, 256, 0, stream>>>(xb, wkb, kw, M_, C_, C_, flagp, 0);
  gemm128<<<gg, 256, 0, stream>>>(xb, wvb, vw, M_, C_, C_, flagp, 0);

  fuse_rope_vmix<<<(M_ * H_) / 4, 256, 0, stream>>>(
      flagp, (__hip_bfloat16*)qw, (__hip_bfloat16*)kw, (__hip_bfloat16*)vw,
      v1, lamb);

  // V -> VT (xb is dead now)
  transp_v<<<dim3(T_ / 64, B_ * H_), 256, 0, stream>>>(vw, vtb);

  attn_mfma<<<dim3(T_ / 128, B_ * H_), 256, 0, stream>>>(qw, kw, vtb, qw);

  gemm128<<<gg, 256, 0, stream>>>(qw, wpb, d_out, M_, C_, C_, flagp, 1);
  copy_v1<<<8192, 256, 0, stream>>>(flagp, v1, d_out);
}